// Round 6
// baseline (163.573 us; speedup 1.0000x reference)
//
#include <hip/hip_runtime.h>

// MinEuclideanDistBlock: x(32,8,4096) f32, shapelets(8,128,64) f32 -> out(32,1,128) f32
// out[b,k] = min_w sum_c sqrt( xnorm[b,c,w] + snorm[c,k] - 2*sum_s x[b,c,w+s]*h[c,k,s] )
//
// R5 -> R6 (post-mortem: K-split duplicated preamble; barrier-paced thin iters):
//  - back to full K=128 per block, 1024 blocks (R3 grid).
//  - x staged ONCE for all 8 channels (4 shifted bf16 copies, 13KB); A-frags via
//    2x ds_read_b64. No per-iter x staging/packing in the barrier-paced loop.
//  - per c-iter: only Bs (20KB) staged from regs prefetched during compute(c-1).
//    Compute per barrier pair: 32 MFMA + 64 sqrt (2x R3/R5).
//  - __launch_bounds__(256,3): cap ~170 VGPR (est use ~150, no spill), 3 blocks/CU.

typedef short short8 __attribute__((ext_vector_type(8)));
typedef float f32x4 __attribute__((ext_vector_type(4)));

constexpr int Bn = 32, Cn = 8, Ln = 4096, Kn = 128, Sn = 64;
constexpr int Wn = Ln - Sn + 1;          // 4033
constexpr int WT = 128;                  // windows per block
constexpr int NWT = (Wn + WT - 1) / WT;  // 32
constexpr int BDIM = 256;

__device__ __forceinline__ unsigned int f2bf(float f) {
  unsigned int u = __float_as_uint(f);
  u += 0x7FFFu + ((u >> 16) & 1u);       // round-to-nearest-even
  return u >> 16;
}

// ws layout: [0, 128KB): ushort hbf[C][K][S] = bf16(-2*h);  [128KB, +4KB): float snorm[C][K]
__global__ void prep_kernel(const float* __restrict__ sh,
                            unsigned int* __restrict__ out,
                            unsigned short* __restrict__ hbf,
                            float* __restrict__ snorm) {
  int gid = blockIdx.x * blockDim.x + threadIdx.x;  // 0..4095
  out[gid] = 0x7F7FFFFFu;                           // FLT_MAX bits (Bn*Kn == 4096)
  if (gid < Cn * Kn) {
    const float4* row = (const float4*)(sh + (size_t)gid * Sn);
    uint2* orow = (uint2*)(hbf + (size_t)gid * Sn);
    float a = 0.f;
    #pragma unroll
    for (int i = 0; i < 16; ++i) {
      float4 v = row[i];
      a += v.x * v.x + v.y * v.y + v.z * v.z + v.w * v.w;
      unsigned int p0 = f2bf(-2.f * v.x) | (f2bf(-2.f * v.y) << 16);
      unsigned int p1 = f2bf(-2.f * v.z) | (f2bf(-2.f * v.w) << 16);
      orow[i] = make_uint2(p0, p1);
    }
    snorm[gid] = a;
  }
}

__launch_bounds__(BDIM, 3)
__global__ void med_kernel(const float* __restrict__ x,
                           const unsigned short* __restrict__ hbf,
                           const float* __restrict__ snorm,
                           unsigned int* __restrict__ out) {
  constexpr int XAS = 204;   // u16 per shift-copy (408B, 8B-aligned rows)
  constexpr int XCS = 4 * XAS;  // per-channel (4 shifted copies)
  constexpr int BSS = 80;    // Bs row stride (elems); 160B = 40 words (8 mod 32)
  __shared__ __align__(16) unsigned short Xs[Cn * XCS];   // 13056 B
  __shared__ __align__(16) unsigned short Bs[Kn * BSS];   // 20480 B
  __shared__ __align__(16) float xnormC[Cn * WT];         // 4 KB
  __shared__ __align__(16) float snormC[Cn * Kn];         // 4 KB
  __shared__ unsigned int smin[Kn];                       // 512 B

  const int tid  = threadIdx.x;
  const int b    = blockIdx.y;
  const int w0   = blockIdx.x * WT;
  const int lane = tid & 63;
  const int wv   = tid >> 6;     // wave 0..3
  const int quad = lane >> 4;    // 0..3
  const int n16  = lane & 15;
  const int wbase = wv * 32;     // this wave's window offset in tile

  const float* xb = x + (size_t)b * Cn * Ln;
  const uint4* hb4 = (const uint4*)hbf;   // per c: 1024 uint4

  // ---- prefetch channel 0's B tile (lands under the preamble) ----
  uint4 Breg[4];
  #pragma unroll
  for (int rep = 0; rep < 4; ++rep) Breg[rep] = hb4[tid + rep * BDIM];

  // ---- stage x for ALL channels: 4 shifted bf16 copies, zero-padded ----
  {
    const int e = tid;                   // element offset within tile
    const bool act = (e < 196);
    float xv[Cn];
    #pragma unroll
    for (int c = 0; c < Cn; ++c)
      xv[c] = (act && (w0 + e) < Ln) ? xb[c * Ln + w0 + e] : 0.f;
    if (act) {
      #pragma unroll
      for (int c = 0; c < Cn; ++c) {
        unsigned short v = (unsigned short)f2bf(xv[c]);
        #pragma unroll
        for (int r = 0; r < 4; ++r) {
          int t = e - r;
          if (t >= 0) Xs[c * XCS + r * XAS + t] = v;
        }
      }
    }
  }

  // snorm: one float4 per thread from prep output (1024 floats)
  ((float4*)snormC)[tid] = ((const float4*)snorm)[tid];
  if (tid < Kn) smin[tid] = 0x7F7FFFFFu;

  // xnorm: 256 threads = 8c x 32 groups, 4 windows each (rolling update), fp32-exact
  {
    int c  = tid >> 5;
    int m0 = (tid & 31) * 4;
    const float* xc = xb + c * Ln;
    auto xq = [&](int i) -> float {
      float v = (i < Ln) ? xc[i] : 0.f;
      return v * v;
    };
    float s0 = 0.f;
    for (int s = 0; s < Sn; ++s) s0 += xq(w0 + m0 + s);
    float s1 = s0 - xq(w0 + m0 + 0) + xq(w0 + m0 + 64);
    float s2 = s1 - xq(w0 + m0 + 1) + xq(w0 + m0 + 65);
    float s3 = s2 - xq(w0 + m0 + 2) + xq(w0 + m0 + 66);
    xnormC[c * WT + m0 + 0] = s0;
    xnormC[c * WT + m0 + 1] = s1;
    xnormC[c * WT + m0 + 2] = s2;
    xnormC[c * WT + m0 + 3] = s3;
  }

  // per-thread A-fragment addressing constants (copy r4, 8B-aligned t)
  const int r4  = n16 & 3;
  const int t00 = wbase + (n16 & ~3) + quad * 8;
  const int bk  = tid >> 3, bch = tid & 7;   // Bs staging coords

  float dist[2][8][4] = {};  // [mtile][nt][reg] summed distance over c

  for (int c = 0; c < Cn; ++c) {
    __syncthreads();  // consumers of Bs(c-1) done (also covers preamble writes)

    // ---- stage phase: pure reg -> LDS (4x ds_write_b128) ----
    #pragma unroll
    for (int rep = 0; rep < 4; ++rep)
      *(uint4*)(&Bs[(bk + rep * 32) * BSS + bch * 8]) = Breg[rep];
    __syncthreads();

    // ---- prefetch next channel's B tile (lands during compute below) ----
    if (c < Cn - 1) {
      #pragma unroll
      for (int rep = 0; rep < 4; ++rep)
        Breg[rep] = hb4[(c + 1) * 1024 + tid + rep * BDIM];
    }

    // xnorm for this wave's 32 windows (C/D row = quad*4+reg)
    float4 xn[2];
    #pragma unroll
    for (int mt = 0; mt < 2; ++mt)
      xn[mt] = *(const float4*)(&xnormC[c * WT + wbase + mt * 16 + quad * 4]);

    // A fragments from the 4-copy layout: two ds_read_b64 each
    short8 af[2][2];
    #pragma unroll
    for (int mt = 0; mt < 2; ++mt)
      #pragma unroll
      for (int ks = 0; ks < 2; ++ks) {
        const unsigned short* pa = &Xs[c * XCS + r4 * XAS + t00 + mt * 16 + ks * 32];
        uint2 a0 = *(const uint2*)(pa);
        uint2 a1 = *(const uint2*)(pa + 4);
        uint4 q = make_uint4(a0.x, a0.y, a1.x, a1.y);
        af[mt][ks] = __builtin_bit_cast(short8, q);
      }

    #pragma unroll
    for (int nt = 0; nt < 8; ++nt) {
      int ksh = nt * 16 + n16;
      float sn = snormC[c * Kn + ksh];
      short8 b0 = *(const short8*)(&Bs[ksh * BSS + quad * 8]);
      short8 b1 = *(const short8*)(&Bs[ksh * BSS + 32 + quad * 8]);
      #pragma unroll
      for (int mt = 0; mt < 2; ++mt) {
        f32x4 acc;
        #pragma unroll
        for (int rg = 0; rg < 4; ++rg) acc[rg] = xn[mt][rg] + sn;
        acc = __builtin_amdgcn_mfma_f32_16x16x32_bf16(af[mt][0], b0, acc, 0, 0, 0);
        acc = __builtin_amdgcn_mfma_f32_16x16x32_bf16(af[mt][1], b1, acc, 0, 0, 0);
        // acc == d2 (norms preloaded in C, -2 folded into B)
        #pragma unroll
        for (int rg = 0; rg < 4; ++rg)
          dist[mt][nt][rg] += __builtin_amdgcn_sqrtf(acc[rg]);
      }
    }
  }

  // ---- min over windows: lane -> wave -> block(LDS) -> global ----
  const int wql = w0 + wbase + quad * 4;
  #pragma unroll
  for (int nt = 0; nt < 8; ++nt) {
    float v = 3.4e38f;
    #pragma unroll
    for (int mt = 0; mt < 2; ++mt)
      #pragma unroll
      for (int rg = 0; rg < 4; ++rg) {
        int wg = wql + mt * 16 + rg;
        float d = (wg < Wn) ? dist[mt][nt][rg] : 3.4e38f;
        v = fminf(v, d);
      }
    v = fminf(v, __shfl_xor(v, 16, 64));
    v = fminf(v, __shfl_xor(v, 32, 64));
    if (lane < 16)
      atomicMin(&smin[nt * 16 + n16], __float_as_uint(v));
  }
  __syncthreads();
  if (tid < Kn)
    atomicMin(&out[b * Kn + tid], smin[tid]);
}

extern "C" void kernel_launch(void* const* d_in, const int* in_sizes, int n_in,
                              void* d_out, int out_size, void* d_ws, size_t ws_size,
                              hipStream_t stream) {
  const float* x  = (const float*)d_in[0];
  const float* sh = (const float*)d_in[1];
  unsigned int* out = (unsigned int*)d_out;
  unsigned short* hbf = (unsigned short*)d_ws;                  // 128 KB
  float* snorm = (float*)((char*)d_ws + (size_t)Cn * Kn * Sn * 2);  // +4 KB
  hipLaunchKernelGGL(prep_kernel, dim3(16), dim3(256), 0, stream, sh, out, hbf, snorm);
  hipLaunchKernelGGL(med_kernel, dim3(NWT, Bn), dim3(BDIM), 0, stream, x, hbf, snorm, out);
}

// Round 7
// 118.716 us; speedup vs baseline: 1.3779x; 1.3779x over previous
//
#include <hip/hip_runtime.h>

// MinEuclideanDistBlock: x(32,8,4096) f32, shapelets(8,128,64) f32 -> out(32,1,128) f32
// out[b,k] = min_w sum_c sqrt( xnorm[b,c,w] + snorm[c,k] - 2*sum_s x[b,c,w+s]*h[c,k,s] )
//
// R6 -> R7 (post-mortem: __launch_bounds__ min-waves is a HARD cap the compiler
// meets by spilling: (256,3) gave VGPR 84 + 140MB scratch writes = the whole
// regression; (256,2) is the only spill-free setting for this ~150-reg kernel):
//  - single change: __launch_bounds__(256, 2). Everything else identical to R6:
//    x staged once for all channels (4 shifted bf16 copies), per-iter Bs staged
//    from regs prefetched during compute(c-1), block-LDS min epilogue.

typedef short short8 __attribute__((ext_vector_type(8)));
typedef float f32x4 __attribute__((ext_vector_type(4)));

constexpr int Bn = 32, Cn = 8, Ln = 4096, Kn = 128, Sn = 64;
constexpr int Wn = Ln - Sn + 1;          // 4033
constexpr int WT = 128;                  // windows per block
constexpr int NWT = (Wn + WT - 1) / WT;  // 32
constexpr int BDIM = 256;

__device__ __forceinline__ unsigned int f2bf(float f) {
  unsigned int u = __float_as_uint(f);
  u += 0x7FFFu + ((u >> 16) & 1u);       // round-to-nearest-even
  return u >> 16;
}

// ws layout: [0, 128KB): ushort hbf[C][K][S] = bf16(-2*h);  [128KB, +4KB): float snorm[C][K]
__global__ void prep_kernel(const float* __restrict__ sh,
                            unsigned int* __restrict__ out,
                            unsigned short* __restrict__ hbf,
                            float* __restrict__ snorm) {
  int gid = blockIdx.x * blockDim.x + threadIdx.x;  // 0..4095
  out[gid] = 0x7F7FFFFFu;                           // FLT_MAX bits (Bn*Kn == 4096)
  if (gid < Cn * Kn) {
    const float4* row = (const float4*)(sh + (size_t)gid * Sn);
    uint2* orow = (uint2*)(hbf + (size_t)gid * Sn);
    float a = 0.f;
    #pragma unroll
    for (int i = 0; i < 16; ++i) {
      float4 v = row[i];
      a += v.x * v.x + v.y * v.y + v.z * v.z + v.w * v.w;
      unsigned int p0 = f2bf(-2.f * v.x) | (f2bf(-2.f * v.y) << 16);
      unsigned int p1 = f2bf(-2.f * v.z) | (f2bf(-2.f * v.w) << 16);
      orow[i] = make_uint2(p0, p1);
    }
    snorm[gid] = a;
  }
}

__launch_bounds__(BDIM, 2)
__global__ void med_kernel(const float* __restrict__ x,
                           const unsigned short* __restrict__ hbf,
                           const float* __restrict__ snorm,
                           unsigned int* __restrict__ out) {
  constexpr int XAS = 204;   // u16 per shift-copy (408B, 8B-aligned rows)
  constexpr int XCS = 4 * XAS;  // per-channel (4 shifted copies)
  constexpr int BSS = 80;    // Bs row stride (elems); 160B = 40 words (8 mod 32)
  __shared__ __align__(16) unsigned short Xs[Cn * XCS];   // 13056 B
  __shared__ __align__(16) unsigned short Bs[Kn * BSS];   // 20480 B
  __shared__ __align__(16) float xnormC[Cn * WT];         // 4 KB
  __shared__ __align__(16) float snormC[Cn * Kn];         // 4 KB
  __shared__ unsigned int smin[Kn];                       // 512 B

  const int tid  = threadIdx.x;
  const int b    = blockIdx.y;
  const int w0   = blockIdx.x * WT;
  const int lane = tid & 63;
  const int wv   = tid >> 6;     // wave 0..3
  const int quad = lane >> 4;    // 0..3
  const int n16  = lane & 15;
  const int wbase = wv * 32;     // this wave's window offset in tile

  const float* xb = x + (size_t)b * Cn * Ln;
  const uint4* hb4 = (const uint4*)hbf;   // per c: 1024 uint4

  // ---- prefetch channel 0's B tile (lands under the preamble) ----
  uint4 Breg[4];
  #pragma unroll
  for (int rep = 0; rep < 4; ++rep) Breg[rep] = hb4[tid + rep * BDIM];

  // ---- stage x for ALL channels: 4 shifted bf16 copies, zero-padded ----
  {
    const int e = tid;                   // element offset within tile
    const bool act = (e < 196);
    float xv[Cn];
    #pragma unroll
    for (int c = 0; c < Cn; ++c)
      xv[c] = (act && (w0 + e) < Ln) ? xb[c * Ln + w0 + e] : 0.f;
    if (act) {
      #pragma unroll
      for (int c = 0; c < Cn; ++c) {
        unsigned short v = (unsigned short)f2bf(xv[c]);
        #pragma unroll
        for (int r = 0; r < 4; ++r) {
          int t = e - r;
          if (t >= 0) Xs[c * XCS + r * XAS + t] = v;
        }
      }
    }
  }

  // snorm: one float4 per thread from prep output (1024 floats)
  ((float4*)snormC)[tid] = ((const float4*)snorm)[tid];
  if (tid < Kn) smin[tid] = 0x7F7FFFFFu;

  // xnorm: 256 threads = 8c x 32 groups, 4 windows each (rolling update), fp32-exact
  {
    int c  = tid >> 5;
    int m0 = (tid & 31) * 4;
    const float* xc = xb + c * Ln;
    auto xq = [&](int i) -> float {
      float v = (i < Ln) ? xc[i] : 0.f;
      return v * v;
    };
    float s0 = 0.f;
    for (int s = 0; s < Sn; ++s) s0 += xq(w0 + m0 + s);
    float s1 = s0 - xq(w0 + m0 + 0) + xq(w0 + m0 + 64);
    float s2 = s1 - xq(w0 + m0 + 1) + xq(w0 + m0 + 65);
    float s3 = s2 - xq(w0 + m0 + 2) + xq(w0 + m0 + 66);
    xnormC[c * WT + m0 + 0] = s0;
    xnormC[c * WT + m0 + 1] = s1;
    xnormC[c * WT + m0 + 2] = s2;
    xnormC[c * WT + m0 + 3] = s3;
  }

  // per-thread A-fragment addressing constants (copy r4, 8B-aligned t)
  const int r4  = n16 & 3;
  const int t00 = wbase + (n16 & ~3) + quad * 8;
  const int bk  = tid >> 3, bch = tid & 7;   // Bs staging coords

  float dist[2][8][4] = {};  // [mtile][nt][reg] summed distance over c

  for (int c = 0; c < Cn; ++c) {
    __syncthreads();  // consumers of Bs(c-1) done (also covers preamble writes)

    // ---- stage phase: pure reg -> LDS (4x ds_write_b128) ----
    #pragma unroll
    for (int rep = 0; rep < 4; ++rep)
      *(uint4*)(&Bs[(bk + rep * 32) * BSS + bch * 8]) = Breg[rep];
    __syncthreads();

    // ---- prefetch next channel's B tile (lands during compute below) ----
    if (c < Cn - 1) {
      #pragma unroll
      for (int rep = 0; rep < 4; ++rep)
        Breg[rep] = hb4[(c + 1) * 1024 + tid + rep * BDIM];
    }

    // xnorm for this wave's 32 windows (C/D row = quad*4+reg)
    float4 xn[2];
    #pragma unroll
    for (int mt = 0; mt < 2; ++mt)
      xn[mt] = *(const float4*)(&xnormC[c * WT + wbase + mt * 16 + quad * 4]);

    // A fragments from the 4-copy layout: two ds_read_b64 each
    short8 af[2][2];
    #pragma unroll
    for (int mt = 0; mt < 2; ++mt)
      #pragma unroll
      for (int ks = 0; ks < 2; ++ks) {
        const unsigned short* pa = &Xs[c * XCS + r4 * XAS + t00 + mt * 16 + ks * 32];
        uint2 a0 = *(const uint2*)(pa);
        uint2 a1 = *(const uint2*)(pa + 4);
        uint4 q = make_uint4(a0.x, a0.y, a1.x, a1.y);
        af[mt][ks] = __builtin_bit_cast(short8, q);
      }

    #pragma unroll
    for (int nt = 0; nt < 8; ++nt) {
      int ksh = nt * 16 + n16;
      float sn = snormC[c * Kn + ksh];
      short8 b0 = *(const short8*)(&Bs[ksh * BSS + quad * 8]);
      short8 b1 = *(const short8*)(&Bs[ksh * BSS + 32 + quad * 8]);
      #pragma unroll
      for (int mt = 0; mt < 2; ++mt) {
        f32x4 acc;
        #pragma unroll
        for (int rg = 0; rg < 4; ++rg) acc[rg] = xn[mt][rg] + sn;
        acc = __builtin_amdgcn_mfma_f32_16x16x32_bf16(af[mt][0], b0, acc, 0, 0, 0);
        acc = __builtin_amdgcn_mfma_f32_16x16x32_bf16(af[mt][1], b1, acc, 0, 0, 0);
        // acc == d2 (norms preloaded in C, -2 folded into B)
        #pragma unroll
        for (int rg = 0; rg < 4; ++rg)
          dist[mt][nt][rg] += __builtin_amdgcn_sqrtf(acc[rg]);
      }
    }
  }

  // ---- min over windows: lane -> wave -> block(LDS) -> global ----
  const int wql = w0 + wbase + quad * 4;
  #pragma unroll
  for (int nt = 0; nt < 8; ++nt) {
    float v = 3.4e38f;
    #pragma unroll
    for (int mt = 0; mt < 2; ++mt)
      #pragma unroll
      for (int rg = 0; rg < 4; ++rg) {
        int wg = wql + mt * 16 + rg;
        float d = (wg < Wn) ? dist[mt][nt][rg] : 3.4e38f;
        v = fminf(v, d);
      }
    v = fminf(v, __shfl_xor(v, 16, 64));
    v = fminf(v, __shfl_xor(v, 32, 64));
    if (lane < 16)
      atomicMin(&smin[nt * 16 + n16], __float_as_uint(v));
  }
  __syncthreads();
  if (tid < Kn)
    atomicMin(&out[b * Kn + tid], smin[tid]);
}

extern "C" void kernel_launch(void* const* d_in, const int* in_sizes, int n_in,
                              void* d_out, int out_size, void* d_ws, size_t ws_size,
                              hipStream_t stream) {
  const float* x  = (const float*)d_in[0];
  const float* sh = (const float*)d_in[1];
  unsigned int* out = (unsigned int*)d_out;
  unsigned short* hbf = (unsigned short*)d_ws;                  // 128 KB
  float* snorm = (float*)((char*)d_ws + (size_t)Cn * Kn * Sn * 2);  // +4 KB
  hipLaunchKernelGGL(prep_kernel, dim3(16), dim3(256), 0, stream, sh, out, hbf, snorm);
  hipLaunchKernelGGL(med_kernel, dim3(NWT, Bn), dim3(BDIM), 0, stream, x, hbf, snorm, out);
}